// Round 5
// baseline (76.107 us; speedup 1.0000x reference)
//
#include <hip/hip_runtime.h>
#include <math.h>

#define THREADS 256

typedef float f2v __attribute__((ext_vector_type(2)));
typedef float f4v __attribute__((ext_vector_type(4)));

// ---- codebook: fp32 levels exactly as numpy float32 computes them ----
static constexpr float kLvl[16] = {
    0.0f      / 0.75f, 0.015625f / 0.75f, 0.03125f / 0.75f, 0.046875f / 0.75f,
    0.0625f   / 0.75f, 0.09375f  / 0.75f, 0.125f   / 0.75f, 0.140625f / 0.75f,
    0.1875f   / 0.75f, 0.25f     / 0.75f, 0.28125f / 0.75f, 0.375f    / 0.75f,
    0.5f      / 0.75f, 0.515625f / 0.75f, 0.5625f  / 0.75f, 0.75f     / 0.75f,
};
// exact f64 midpoints of adjacent f32 levels: strict a>mid == numpy f32 argmin (Sterbenz)
static constexpr double kMid[15] = {
    ((double)kLvl[0]  + (double)kLvl[1])  * 0.5, ((double)kLvl[1]  + (double)kLvl[2])  * 0.5,
    ((double)kLvl[2]  + (double)kLvl[3])  * 0.5, ((double)kLvl[3]  + (double)kLvl[4])  * 0.5,
    ((double)kLvl[4]  + (double)kLvl[5])  * 0.5, ((double)kLvl[5]  + (double)kLvl[6])  * 0.5,
    ((double)kLvl[6]  + (double)kLvl[7])  * 0.5, ((double)kLvl[7]  + (double)kLvl[8])  * 0.5,
    ((double)kLvl[8]  + (double)kLvl[9])  * 0.5, ((double)kLvl[9]  + (double)kLvl[10]) * 0.5,
    ((double)kLvl[10] + (double)kLvl[11]) * 0.5, ((double)kLvl[11] + (double)kLvl[12]) * 0.5,
    ((double)kLvl[12] + (double)kLvl[13]) * 0.5, ((double)kLvl[13] + (double)kLvl[14]) * 0.5,
    ((double)kLvl[14] + (double)kLvl[15]) * 0.5,
};

// complete-binary-tree sum over 64 lanes (f32 add commutative -> xor butterfly
// reproduces numpy's adjacent-pair tree exactly)
__device__ __forceinline__ float tree64(float v) {
    #pragma unroll
    for (int m = 1; m <= 32; m <<= 1)
        v += __shfl_xor(v, m, 64);
    return v;
}

// broadcast a block-uniform float into an SGPR
__device__ __forceinline__ float sgpr_bcast(float x) {
    return __uint_as_float(__builtin_amdgcn_readfirstlane(__float_as_uint(x)));
}

// ---- leaf pass (unchanged from round 4 — measured at ~6 TB/s, BW roofline).
// 4 lanes per 128-elem numpy leaf; lane r owns accs {2r,2r+1}; xor butterfly
// reproduces numpy's pairwise tree bit-exactly. Block = 64 leaves = 8192 elems.
template<int PASS>
__global__ __launch_bounds__(THREADS) void leaf_pass(const float* __restrict__ w,
                                                     const float* __restrict__ bprev,
                                                     float* __restrict__ bout,
                                                     long long n, int nb) {
    #pragma clang fp contract(off)
    __shared__ float ws4[4];
    __shared__ float smean;
    float mean = 0.0f;
    if (PASS == 1) {
        int i0 = threadIdx.x * 8;
        float v = 0.0f;
        if (i0 + 7 < nb) {
            const float* p = bprev + i0;
            v = ((p[0] + p[1]) + (p[2] + p[3])) + ((p[4] + p[5]) + (p[6] + p[7]));
        }
        v = tree64(v);
        if ((threadIdx.x & 63) == 0) ws4[threadIdx.x >> 6] = v;
        __syncthreads();
        if (threadIdx.x == 0)
            smean = ((ws4[0] + ws4[1]) + (ws4[2] + ws4[3])) / (float)n;
        __syncthreads();
        mean = smean;
    }

    const long long base = (long long)blockIdx.x * 8192
                         + (long long)(threadIdx.x >> 2) * 128
                         + (long long)(threadIdx.x & 3) * 2;
    const f2v* p = (const f2v*)(w + base);
    float s0, s1;
    {
        f2v a = p[0];
        if (PASS == 1) { float x = a.x - mean, y = a.y - mean; s0 = x * x; s1 = y * y; }
        else           { s0 = a.x; s1 = a.y; }
    }
    #pragma unroll
    for (int t = 1; t < 16; ++t) {
        f2v a = p[4 * t];
        if (PASS == 1) { float x = a.x - mean, y = a.y - mean; s0 += x * x; s1 += y * y; }
        else           { s0 += a.x; s1 += a.y; }
    }
    float s = s0 + s1;
    s = tree64(s);
    if ((threadIdx.x & 63) == 0) ws4[threadIdx.x >> 6] = s;
    __syncthreads();
    if (threadIdx.x == 0)
        bout[blockIdx.x] = (ws4[0] + ws4[1]) + (ws4[2] + ws4[3]);
}

// per-element quantize: 1 sub + 1 abs + 15 (v_cmp + v_cndmask) + copysign.
// T/C are SGPR-resident; no LDS, no divides, no f64 in the hot loop.
__device__ __forceinline__ float q1(float v, float mean,
                                    const float* __restrict__ T,
                                    const float* __restrict__ C) {
    float u  = v - mean;
    float au = fabsf(u);
    float o  = C[0];
    #pragma unroll
    for (int k = 0; k < 15; ++k) o = (au < T[k]) ? o : C[k + 1];
    return copysignf(o, u);
}

// ---- quantize with fused finalize: per-block recompute mean/sd from partials,
// pull the 15 decision boundaries back into u = (w-mean) space via monotone
// binary search over f32 bit patterns (bit-exact vs the IEEE f32 chain).
__global__ __launch_bounds__(THREADS) void quantize_k(const f4v* __restrict__ w4,
                                                      f4v* __restrict__ o4,
                                                      const float* __restrict__ bout0,
                                                      const float* __restrict__ bout1,
                                                      const float* __restrict__ alpha_ptr,
                                                      long long n, int nb) {
    #pragma clang fp contract(off)
    __shared__ float wsA[4], wsB[4];
    __shared__ float sP[2];       // mean, sd
    __shared__ float sT[15];      // u-space thresholds
    __shared__ float sC[16];      // output levels (level * alpha)
    {
        int i0 = threadIdx.x * 8;
        float v = 0.0f, u = 0.0f;
        if (i0 + 7 < nb) {
            const float* p0 = bout0 + i0;
            const float* p1 = bout1 + i0;
            v = ((p0[0] + p0[1]) + (p0[2] + p0[3])) + ((p0[4] + p0[5]) + (p0[6] + p0[7]));
            u = ((p1[0] + p1[1]) + (p1[2] + p1[3])) + ((p1[4] + p1[5]) + (p1[6] + p1[7]));
        }
        v = tree64(v);
        u = tree64(u);
        if ((threadIdx.x & 63) == 0) { wsA[threadIdx.x >> 6] = v; wsB[threadIdx.x >> 6] = u; }
        __syncthreads();
        if (threadIdx.x == 0) {
            sP[0] = ((wsA[0] + wsA[1]) + (wsA[2] + wsA[3])) / (float)n;          // mean
            sP[1] = sqrtf(((wsB[0] + wsB[1]) + (wsB[2] + wsB[3])) / (float)(n - 1)); // sd
        }
        __syncthreads();
    }
    const float sd = sP[1];
    const float al = alpha_ptr[0];
    if (threadIdx.x < 15) {
        // smallest f32 u >= 0 whose IEEE f32 chain value exceeds kMid[i]
        const double mid = kMid[threadIdx.x];
        unsigned lo = 0u, hi = 0x7F800000u;        // [+0, +inf]; chain(inf)=1>mid
        while (lo < hi) {
            unsigned m = (lo + hi) >> 1;
            float uu = __uint_as_float(m);
            float y  = uu / sd;                    // f32 IEEE div (matches numpy)
            float x  = y / al;                     // f32 IEEE div
            float xc = fminf(x, 1.0f);             // clip upper (abs domain)
            if ((double)xc > mid) hi = m; else lo = m + 1;
        }
        sT[threadIdx.x] = __uint_as_float(lo);
    } else if (threadIdx.x < 31) {
        int i = threadIdx.x - 15;
        sC[i] = kLvl[i] * al;                      // same bits as ref's level*alpha
    } else if (threadIdx.x == 31) {
        sC[0] = 0.0f;
    }
    __syncthreads();

    // hoist all uniforms into SGPRs (readfirstlane)
    const float mean = sgpr_bcast(sP[0]);
    float T[15], C[16];
    #pragma unroll
    for (int k = 0; k < 15; ++k) T[k] = sgpr_bcast(sT[k]);
    #pragma unroll
    for (int k = 0; k < 16; ++k) C[k] = sgpr_bcast(sC[k]);

    long long n4     = n >> 2;
    long long tid    = (long long)blockIdx.x * THREADS + threadIdx.x;
    long long stride = (long long)gridDim.x * THREADS;

    long long i = tid;
    for (; i + stride < n4; i += 2 * stride) {     // unroll-2: two f4v in flight
        f4v a = w4[i];
        f4v b = w4[i + stride];
        f4v ra, rb;
        ra.x = q1(a.x, mean, T, C);
        ra.y = q1(a.y, mean, T, C);
        ra.z = q1(a.z, mean, T, C);
        ra.w = q1(a.w, mean, T, C);
        rb.x = q1(b.x, mean, T, C);
        rb.y = q1(b.y, mean, T, C);
        rb.z = q1(b.z, mean, T, C);
        rb.w = q1(b.w, mean, T, C);
        o4[i] = ra;
        o4[i + stride] = rb;
    }
    for (; i < n4; i += stride) {                  // tail (unused at n = 2^24)
        f4v a = w4[i];
        f4v ra;
        ra.x = q1(a.x, mean, T, C);
        ra.y = q1(a.y, mean, T, C);
        ra.z = q1(a.z, mean, T, C);
        ra.w = q1(a.w, mean, T, C);
        o4[i] = ra;
    }
}

extern "C" void kernel_launch(void* const* d_in, const int* in_sizes, int n_in,
                              void* d_out, int out_size, void* d_ws, size_t ws_size,
                              hipStream_t stream) {
    const float* w     = (const float*)d_in[0];
    const float* alpha = (const float*)d_in[1];
    float* out = (float*)d_out;
    long long n = (long long)in_sizes[0];          // 16777216 = 2^24

    int nblk = (int)(n >> 13);                     // 8192 elems/block -> 2048 blocks
    float* bout0 = (float*)d_ws;                   // nblk partials (sum)
    float* bout1 = bout0 + nblk;                   // nblk partials (sumsq)

    leaf_pass<0><<<nblk, THREADS, 0, stream>>>(w, nullptr, bout0, n, nblk);
    leaf_pass<1><<<nblk, THREADS, 0, stream>>>(w, bout0, bout1, n, nblk);
    quantize_k<<<2048, THREADS, 0, stream>>>((const f4v*)w, (f4v*)out,
                                             bout0, bout1, alpha, n, nblk);
}

// Round 7
// 54.963 us; speedup vs baseline: 1.3847x; 1.3847x over previous
//
#include <hip/hip_runtime.h>
#include <math.h>

#define THREADS 256

typedef float f2v __attribute__((ext_vector_type(2)));
typedef float f4v __attribute__((ext_vector_type(4)));

// ---- codebook: fp32 levels exactly as numpy float32 computes them ----
static constexpr float kLvl[16] = {
    0.0f      / 0.75f, 0.015625f / 0.75f, 0.03125f / 0.75f, 0.046875f / 0.75f,
    0.0625f   / 0.75f, 0.09375f  / 0.75f, 0.125f   / 0.75f, 0.140625f / 0.75f,
    0.1875f   / 0.75f, 0.25f     / 0.75f, 0.28125f / 0.75f, 0.375f    / 0.75f,
    0.5f      / 0.75f, 0.515625f / 0.75f, 0.5625f  / 0.75f, 0.75f     / 0.75f,
};
// exact f64 midpoints of adjacent f32 levels: strict a>mid == numpy f32 argmin (Sterbenz)
static constexpr double kMid[15] = {
    ((double)kLvl[0]  + (double)kLvl[1])  * 0.5, ((double)kLvl[1]  + (double)kLvl[2])  * 0.5,
    ((double)kLvl[2]  + (double)kLvl[3])  * 0.5, ((double)kLvl[3]  + (double)kLvl[4])  * 0.5,
    ((double)kLvl[4]  + (double)kLvl[5])  * 0.5, ((double)kLvl[5]  + (double)kLvl[6])  * 0.5,
    ((double)kLvl[6]  + (double)kLvl[7])  * 0.5, ((double)kLvl[7]  + (double)kLvl[8])  * 0.5,
    ((double)kLvl[8]  + (double)kLvl[9])  * 0.5, ((double)kLvl[9]  + (double)kLvl[10]) * 0.5,
    ((double)kLvl[10] + (double)kLvl[11]) * 0.5, ((double)kLvl[11] + (double)kLvl[12]) * 0.5,
    ((double)kLvl[12] + (double)kLvl[13]) * 0.5, ((double)kLvl[13] + (double)kLvl[14]) * 0.5,
    ((double)kLvl[14] + (double)kLvl[15]) * 0.5,
};

// complete-binary-tree sum over 64 lanes (f32 add commutative -> xor butterfly
// reproduces numpy's adjacent-pair tree exactly)
__device__ __forceinline__ float tree64(float v) {
    #pragma unroll
    for (int m = 1; m <= 32; m <<= 1)
        v += __shfl_xor(v, m, 64);
    return v;
}

// broadcast a block-uniform float into an SGPR
__device__ __forceinline__ float sgpr_bcast(float x) {
    return __uint_as_float(__builtin_amdgcn_readfirstlane(__float_as_uint(x)));
}

// ---- leaf pass (unchanged — measured ~6 TB/s, BW roofline).
// 4 lanes per 128-elem numpy leaf; lane r owns accs {2r,2r+1}; xor butterfly
// reproduces numpy's pairwise tree bit-exactly. Block = 64 leaves = 8192 elems.
template<int PASS>
__global__ __launch_bounds__(THREADS) void leaf_pass(const float* __restrict__ w,
                                                     const float* __restrict__ bprev,
                                                     float* __restrict__ bout,
                                                     long long n, int nb) {
    #pragma clang fp contract(off)
    __shared__ float ws4[4];
    __shared__ float smean;
    float mean = 0.0f;
    if (PASS == 1) {
        int i0 = threadIdx.x * 8;
        float v = 0.0f;
        if (i0 + 7 < nb) {
            const float* p = bprev + i0;
            v = ((p[0] + p[1]) + (p[2] + p[3])) + ((p[4] + p[5]) + (p[6] + p[7]));
        }
        v = tree64(v);
        if ((threadIdx.x & 63) == 0) ws4[threadIdx.x >> 6] = v;
        __syncthreads();
        if (threadIdx.x == 0)
            smean = ((ws4[0] + ws4[1]) + (ws4[2] + ws4[3])) / (float)n;
        __syncthreads();
        mean = smean;
    }

    const long long base = (long long)blockIdx.x * 8192
                         + (long long)(threadIdx.x >> 2) * 128
                         + (long long)(threadIdx.x & 3) * 2;
    const f2v* p = (const f2v*)(w + base);
    float s0, s1;
    {
        f2v a = p[0];
        if (PASS == 1) { float x = a.x - mean, y = a.y - mean; s0 = x * x; s1 = y * y; }
        else           { s0 = a.x; s1 = a.y; }
    }
    #pragma unroll
    for (int t = 1; t < 16; ++t) {
        f2v a = p[4 * t];
        if (PASS == 1) { float x = a.x - mean, y = a.y - mean; s0 += x * x; s1 += y * y; }
        else           { s0 += a.x; s1 += a.y; }
    }
    float s = s0 + s1;
    s = tree64(s);
    if ((threadIdx.x & 63) == 0) ws4[threadIdx.x >> 6] = s;
    __syncthreads();
    if (threadIdx.x == 0)
        bout[blockIdx.x] = (ws4[0] + ws4[1]) + (ws4[2] + ws4[3]);
}

// named-scalar select chain: mean-subtract + 15 x (v_cmp + v_cndmask),
// no arrays -> no PromoteAlloca, no LDS in the hot loop. copysign = v_bfi.
#define QSEL(V, RES) do {                                   \
    float _u  = (V) - mean;                                 \
    float _au = fabsf(_u);                                  \
    float _o  = c0;                                         \
    _o = (_au < t0)  ? _o : c1;                             \
    _o = (_au < t1)  ? _o : c2;                             \
    _o = (_au < t2)  ? _o : c3;                             \
    _o = (_au < t3)  ? _o : c4;                             \
    _o = (_au < t4)  ? _o : c5;                             \
    _o = (_au < t5)  ? _o : c6;                             \
    _o = (_au < t6)  ? _o : c7;                             \
    _o = (_au < t7)  ? _o : c8;                             \
    _o = (_au < t8)  ? _o : c9;                             \
    _o = (_au < t9)  ? _o : c10;                            \
    _o = (_au < t10) ? _o : c11;                            \
    _o = (_au < t11) ? _o : c12;                            \
    _o = (_au < t12) ? _o : c13;                            \
    _o = (_au < t13) ? _o : c14;                            \
    _o = (_au < t14) ? _o : c15;                            \
    RES = copysignf(_o, _u);                                \
} while (0)

// ---- quantize with fused finalize: per-block recompute mean/sd from partials,
// pull the 15 decision boundaries back into u = (w-mean) space via monotone
// binary search over f32 bit patterns (bit-exact vs the IEEE f32 chain).
__global__ __launch_bounds__(THREADS) void quantize_k(const f4v* __restrict__ w4,
                                                      f4v* __restrict__ o4,
                                                      const float* __restrict__ bout0,
                                                      const float* __restrict__ bout1,
                                                      const float* __restrict__ alpha_ptr,
                                                      long long n, int nb) {
    #pragma clang fp contract(off)
    __shared__ float wsA[4], wsB[4];
    __shared__ float sP[2];       // mean, sd
    __shared__ float sT[15];      // u-space thresholds
    __shared__ float sC[16];      // output levels (level * alpha)
    {
        int i0 = threadIdx.x * 8;
        float v = 0.0f, u = 0.0f;
        if (i0 + 7 < nb) {
            const float* p0 = bout0 + i0;
            const float* p1 = bout1 + i0;
            v = ((p0[0] + p0[1]) + (p0[2] + p0[3])) + ((p0[4] + p0[5]) + (p0[6] + p0[7]));
            u = ((p1[0] + p1[1]) + (p1[2] + p1[3])) + ((p1[4] + p1[5]) + (p1[6] + p1[7]));
        }
        v = tree64(v);
        u = tree64(u);
        if ((threadIdx.x & 63) == 0) { wsA[threadIdx.x >> 6] = v; wsB[threadIdx.x >> 6] = u; }
        __syncthreads();
        if (threadIdx.x == 0) {
            sP[0] = ((wsA[0] + wsA[1]) + (wsA[2] + wsA[3])) / (float)n;              // mean
            sP[1] = sqrtf(((wsB[0] + wsB[1]) + (wsB[2] + wsB[3])) / (float)(n - 1)); // sd
        }
        __syncthreads();
    }
    const float sd = sP[1];
    const float al = alpha_ptr[0];
    if (threadIdx.x < 15) {
        // smallest f32 u >= 0 whose IEEE f32 chain value exceeds kMid[i]
        const double mid = kMid[threadIdx.x];
        unsigned lo = 0u, hi = 0x7F800000u;        // [+0, +inf]; chain(inf)=1>mid
        while (lo < hi) {
            unsigned m = (lo + hi) >> 1;
            float uu = __uint_as_float(m);
            float y  = uu / sd;                    // f32 IEEE div (matches numpy)
            float x  = y / al;                     // f32 IEEE div
            float xc = fminf(x, 1.0f);             // clip upper (abs domain)
            if ((double)xc > mid) hi = m; else lo = m + 1;
        }
        sT[threadIdx.x] = __uint_as_float(lo);
    } else if (threadIdx.x < 31) {
        int i = threadIdx.x - 15;
        sC[i] = kLvl[i] * al;                      // same bits as ref's level*alpha
    } else if (threadIdx.x == 31) {
        sC[0] = 0.0f;
    }
    __syncthreads();

    // hoist all uniforms into NAMED SGPR scalars (no arrays!)
    const float mean = sgpr_bcast(sP[0]);
    const float t0  = sgpr_bcast(sT[0]),  t1  = sgpr_bcast(sT[1]);
    const float t2  = sgpr_bcast(sT[2]),  t3  = sgpr_bcast(sT[3]);
    const float t4  = sgpr_bcast(sT[4]),  t5  = sgpr_bcast(sT[5]);
    const float t6  = sgpr_bcast(sT[6]),  t7  = sgpr_bcast(sT[7]);
    const float t8  = sgpr_bcast(sT[8]),  t9  = sgpr_bcast(sT[9]);
    const float t10 = sgpr_bcast(sT[10]), t11 = sgpr_bcast(sT[11]);
    const float t12 = sgpr_bcast(sT[12]), t13 = sgpr_bcast(sT[13]);
    const float t14 = sgpr_bcast(sT[14]);
    const float c0  = sgpr_bcast(sC[0]),  c1  = sgpr_bcast(sC[1]);
    const float c2  = sgpr_bcast(sC[2]),  c3  = sgpr_bcast(sC[3]);
    const float c4  = sgpr_bcast(sC[4]),  c5  = sgpr_bcast(sC[5]);
    const float c6  = sgpr_bcast(sC[6]),  c7  = sgpr_bcast(sC[7]);
    const float c8  = sgpr_bcast(sC[8]),  c9  = sgpr_bcast(sC[9]);
    const float c10 = sgpr_bcast(sC[10]), c11 = sgpr_bcast(sC[11]);
    const float c12 = sgpr_bcast(sC[12]), c13 = sgpr_bcast(sC[13]);
    const float c14 = sgpr_bcast(sC[14]), c15 = sgpr_bcast(sC[15]);

    long long n4     = n >> 2;
    long long tid    = (long long)blockIdx.x * THREADS + threadIdx.x;
    long long stride = (long long)gridDim.x * THREADS;

    long long i = tid;
    for (; i + stride < n4; i += 2 * stride) {     // unroll-2: two f4v in flight
        f4v a = w4[i];
        f4v b = w4[i + stride];
        f4v ra, rb;
        QSEL(a.x, ra.x); QSEL(a.y, ra.y); QSEL(a.z, ra.z); QSEL(a.w, ra.w);
        QSEL(b.x, rb.x); QSEL(b.y, rb.y); QSEL(b.z, rb.z); QSEL(b.w, rb.w);
        __builtin_nontemporal_store(ra, &o4[i]);
        __builtin_nontemporal_store(rb, &o4[i + stride]);
    }
    for (; i < n4; i += stride) {                  // tail (unused at n = 2^24)
        f4v a = w4[i];
        f4v ra;
        QSEL(a.x, ra.x); QSEL(a.y, ra.y); QSEL(a.z, ra.z); QSEL(a.w, ra.w);
        __builtin_nontemporal_store(ra, &o4[i]);
    }
}

extern "C" void kernel_launch(void* const* d_in, const int* in_sizes, int n_in,
                              void* d_out, int out_size, void* d_ws, size_t ws_size,
                              hipStream_t stream) {
    const float* w     = (const float*)d_in[0];
    const float* alpha = (const float*)d_in[1];
    float* out = (float*)d_out;
    long long n = (long long)in_sizes[0];          // 16777216 = 2^24

    int nblk = (int)(n >> 13);                     // 8192 elems/block -> 2048 blocks
    float* bout0 = (float*)d_ws;                   // nblk partials (sum)
    float* bout1 = bout0 + nblk;                   // nblk partials (sumsq)

    leaf_pass<0><<<nblk, THREADS, 0, stream>>>(w, nullptr, bout0, n, nblk);
    leaf_pass<1><<<nblk, THREADS, 0, stream>>>(w, bout0, bout1, n, nblk);
    quantize_k<<<2048, THREADS, 0, stream>>>((const f4v*)w, (f4v*)out,
                                             bout0, bout1, alpha, n, nblk);
}